// Round 13
// baseline (5143.645 us; speedup 1.0000x reference)
//
#include <hip/hip_runtime.h>
#include <stdint.h>

#define M_DIM 8192
#define K_DIM 4096
#define N_DIM 4096
#define KTILES (K_DIM / 64)

typedef __attribute__((ext_vector_type(4))) int i32x4;

// ---------------------------------------------------------------------------
// Pack int32-stored int8 weights [N,K] -> true int8 [N,K]; per-row sum folded
// into integer correction corr[n] = (128 - zp) * rowsum[n].
// ---------------------------------------------------------------------------
__global__ void pack_w_kernel(const int* __restrict__ w, char* __restrict__ wp,
                              int* __restrict__ corr, const int* __restrict__ zpp) {
  __shared__ int red[256];
  const int n = blockIdx.x;
  const int t = threadIdx.x;
  const int4* row = (const int4*)(w + (size_t)n * K_DIM);
  int s = 0;
  int words[4];
#pragma unroll
  for (int u = 0; u < 4; ++u) {
    int4 v = row[t * 4 + u];
    s += v.x + v.y + v.z + v.w;
    words[u] = (v.x & 255) | ((v.y & 255) << 8) | ((v.z & 255) << 16) | (v.w << 24);
  }
  ((int4*)(wp + (size_t)n * K_DIM))[t] = make_int4(words[0], words[1], words[2], words[3]);
  red[t] = s;
  __syncthreads();
  for (int off = 128; off > 0; off >>= 1) {
    if (t < off) red[t] += red[t + off];
    __syncthreads();
  }
  if (t == 0) corr[n] = (128 - zpp[0]) * red[0];
}

// ---------------------------------------------------------------------------
// Quantize fp32 input -> int8 (q - 128), 4 elements/thread.
// ---------------------------------------------------------------------------
__global__ void quant_in_kernel(const float* __restrict__ x, char* __restrict__ q,
                                const float* __restrict__ sp, const int* __restrict__ zpp) {
  const int i = blockIdx.x * blockDim.x + threadIdx.x;
  const float s = sp[0];
  const float zp = (float)zpp[0];
  float4 v = ((const float4*)x)[i];
  float t0 = fminf(fmaxf(rintf(v.x / s) + zp, 0.f), 255.f);
  float t1 = fminf(fmaxf(rintf(v.y / s) + zp, 0.f), 255.f);
  float t2 = fminf(fmaxf(rintf(v.z / s) + zp, 0.f), 255.f);
  float t3 = fminf(fmaxf(rintf(v.w / s) + zp, 0.f), 255.f);
  int b0 = (int)t0 - 128, b1 = (int)t1 - 128, b2 = (int)t2 - 128, b3 = (int)t3 - 128;
  ((int*)q)[i] = (b0 & 255) | ((b1 & 255) << 8) | ((b2 & 255) << 16) | (b3 << 24);
}

// ---------------------------------------------------------------------------
// 256x512 i8 GEMM, 8 waves (2M x 4N), 128x128 out per wave.
// Rationale: R3-R12 floor 135us = per-K-step serial sum {MFMA 1306/SIMD +
// LDS ~1236/CU}. The LDS term is READ AMPLIFICATION (3x: A x4 waves, B x2).
// 128x128/wave cuts amplification to 2x while doubling MFMA per K-step:
// LDS/MFMA 0.95 -> 0.73 -> serial-sum ~121us/GEMM in ONE 256-block round.
// LDS: 3-slot ring x 48KB (A 16KB + B 32KB) = 144KB <= 160, 1 block/CU.
// Ledger (dist 2): 6 stages/tile; vmcnt(6) at tile-t end retires everything
// except t+2's stages -> slot t+1 confirmed for next-reads; stage during t
// targets slot (t-1)%3, whose reads finished before t-1's end barrier.
// Tail: clamped dead re-stages keep the ledger uniform.
// Swizzle (0-conflict R1-R12): phys 16B slot = g ^ ((row>>1)&3) on staging
// source and ds_read addr (16-lane phases: <=2 lanes/16B position).
// B content permutation (R8/R9-validated, per 64-row group): LDS row rho
// holds weight row (rho&~63)+4*(rho&15)+((rho>>4)&3) -> epilogue n =
// base+4c+jj consecutive -> packed full-line stores (WRITE_SIZE = 32MB).
// Regs: acc 8x8 frags = 256 AGPR + ~110 VGPR = ~366/wave; 2 waves/SIMD fits.
// ---------------------------------------------------------------------------
#define STAGE16(SRC, DST)                                                     \
  __builtin_amdgcn_global_load_lds(                                           \
      (const __attribute__((address_space(1))) void*)(SRC),                   \
      (__attribute__((address_space(3))) void*)(DST), 16, 0, 0)

#define RD(p) (*(const i32x4*)(p))

#define TILE3(SLOT, KS, DO_NEXT)                                              \
  {                                                                           \
    const char* cur_ = &lds[SLOT][0];                                         \
    char* nxt_ = &lds[((SLOT) + 2) % 3][0];                                   \
    i32x4 a1_[4];                                                             \
    _Pragma("unroll") for (int i_ = 0; i_ < 4; ++i_)                          \
        a1_[i_] = RD(cur_ + aoff[4 + i_]);                                    \
    STAGE16(asr[0] + (size_t)(KS), nxt_ + oa0);                               \
    STAGE16(asr[1] + (size_t)(KS), nxt_ + oa1);                               \
    STAGE16(bsr[0] + (size_t)(KS), nxt_ + ob0);                               \
    __builtin_amdgcn_s_setprio(1);                                            \
    _Pragma("unroll") for (int i_ = 0; i_ < 4; ++i_)                          \
        _Pragma("unroll") for (int j_ = 0; j_ < 8; ++j_)                      \
            acc[i_][j_] = __builtin_amdgcn_mfma_i32_16x16x64_i8(              \
                a0[i_], b0[j_], acc[i_][j_], 0, 0, 0);                        \
    __builtin_amdgcn_s_setprio(0);                                            \
    i32x4 ta_[4], tb_[8];                                                     \
    if (DO_NEXT) {                                                            \
      const char* nx1_ = &lds[((SLOT) + 1) % 3][0];                           \
      _Pragma("unroll") for (int i_ = 0; i_ < 4; ++i_)                        \
          ta_[i_] = RD(nx1_ + aoff[i_]);                                      \
      _Pragma("unroll") for (int j_ = 0; j_ < 8; ++j_)                        \
          tb_[j_] = RD(nx1_ + boff[j_]);                                      \
    }                                                                         \
    STAGE16(bsr[1] + (size_t)(KS), nxt_ + ob1);                               \
    STAGE16(bsr[2] + (size_t)(KS), nxt_ + ob2);                               \
    STAGE16(bsr[3] + (size_t)(KS), nxt_ + ob3);                               \
    __builtin_amdgcn_s_setprio(1);                                            \
    _Pragma("unroll") for (int i_ = 0; i_ < 4; ++i_)                          \
        _Pragma("unroll") for (int j_ = 0; j_ < 8; ++j_)                      \
            acc[4 + i_][j_] = __builtin_amdgcn_mfma_i32_16x16x64_i8(          \
                a1_[i_], b0[j_], acc[4 + i_][j_], 0, 0, 0);                   \
    __builtin_amdgcn_s_setprio(0);                                            \
    asm volatile("s_waitcnt vmcnt(6)" ::: "memory");                          \
    __builtin_amdgcn_s_barrier();                                             \
    if (DO_NEXT) {                                                            \
      _Pragma("unroll") for (int i_ = 0; i_ < 4; ++i_) a0[i_] = ta_[i_];      \
      _Pragma("unroll") for (int j_ = 0; j_ < 8; ++j_) b0[j_] = tb_[j_];      \
    }                                                                         \
  }

template <int WRITE_Q>
__global__ __launch_bounds__(512, 2) void gemm_kernel(
    const char* __restrict__ qa, const char* __restrict__ wb,
    const int* __restrict__ corr, const float* __restrict__ swp,
    const float* __restrict__ bias, const float* __restrict__ sp,
    const int* __restrict__ zpp, char* __restrict__ outq, float* __restrict__ outf) {
  __shared__ __align__(16) char lds[3][49152];  // 144 KB: 3-slot ring, A@0 B@16K
  const int tid = threadIdx.x;
  const int lane = tid & 63;
  const int w = tid >> 6;
  const int wr = w >> 2;   // 0..1 (M, 128 each)
  const int wc = w & 3;    // 0..3 (N, 128 each)
  const int bid = blockIdx.x;
  const int bm = bid & 31;  // M/256 = 32, fastest: neighbors share B panel
  const int bn = bid >> 5;  // N/512 = 8
  const char* abase = qa + (size_t)bm * 256 * K_DIM;
  const char* bbase = wb + (size_t)bn * 512 * K_DIM;

  // --- staging constants ---
  // A: 16 KB = 2 chunks of 8 KB (512 thr x 16 B); rows 0..255.
  const int oa0 = tid * 16;
  const int oa1 = 8192 + tid * 16;
  // B: 32 KB = 4 chunks; LDS offsets 16384 + c*8192 + tid*16; rows 0..511.
  const int ob0 = 16384 + tid * 16;
  const int ob1 = 16384 + 8192 + tid * 16;
  const int ob2 = 16384 + 16384 + tid * 16;
  const int ob3 = 16384 + 24576 + tid * 16;
  const char* asr[2];
  const char* bsr[4];
  {
    const int sl = tid & 3;  // 16B slot within row, both A and B chunks
#pragma unroll
    for (int c = 0; c < 2; ++c) {
      const int r = (c * 8192 + tid * 16) >> 6;  // 0..255
      const int gsw = sl ^ ((r >> 1) & 3);
      asr[c] = abase + (size_t)r * K_DIM + gsw * 16;
    }
#pragma unroll
    for (int c = 0; c < 4; ++c) {
      const int rho = (c * 8192 + tid * 16) >> 6;  // 0..511
      const int gsw = sl ^ ((rho >> 1) & 3);
      const int prm = (rho & ~63) + 4 * (rho & 15) + ((rho >> 4) & 3);
      bsr[c] = bbase + (size_t)prm * K_DIM + gsw * 16;
    }
  }

  // --- per-lane ds_read byte offsets (swizzled) ---
  const int rr = lane & 15;
  const int g = lane >> 4;
  int aoff[8], boff[8];
#pragma unroll
  for (int i = 0; i < 8; ++i) {
    const int rowA = wr * 128 + i * 16 + rr;
    aoff[i] = (rowA << 6) + ((g ^ ((rowA >> 1) & 3)) << 4);
    const int rowB = wc * 128 + i * 16 + rr;
    boff[i] = 16384 + (rowB << 6) + ((g ^ ((rowB >> 1) & 3)) << 4);
  }

  i32x4 acc[8][8] = {};

  // --- prologue: stage slots 0,1 (tiles 0,1; 6 ops each); confirm slot 0 ---
#pragma unroll
  for (int s_ = 0; s_ < 2; ++s_) {
    STAGE16(asr[0] + s_ * 64, &lds[s_][0] + oa0);
    STAGE16(asr[1] + s_ * 64, &lds[s_][0] + oa1);
    STAGE16(bsr[0] + s_ * 64, &lds[s_][0] + ob0);
    STAGE16(bsr[1] + s_ * 64, &lds[s_][0] + ob1);
    STAGE16(bsr[2] + s_ * 64, &lds[s_][0] + ob2);
    STAGE16(bsr[3] + s_ * 64, &lds[s_][0] + ob3);
  }
  asm volatile("s_waitcnt vmcnt(6)" ::: "memory");  // slot 0 confirmed
  __builtin_amdgcn_s_barrier();

  i32x4 a0[4], b0[8];
#pragma unroll
  for (int i = 0; i < 4; ++i) a0[i] = RD(&lds[0][0] + aoff[i]);
#pragma unroll
  for (int j = 0; j < 8; ++j) b0[j] = RD(&lds[0][0] + boff[j]);

  // --- main loop: tiles 0..62 (21 x 3 slots); tail tile 63 ---
#define KCL(x) ((size_t)((x) < KTILES ? (x) : KTILES - 1) * 64)
  for (int t3 = 0; t3 < 21; ++t3) {
    const int t0 = t3 * 3;
    TILE3(0, KCL(t0 + 2), 1)
    TILE3(1, KCL(t0 + 3), 1)
    TILE3(2, KCL(t0 + 4), 1)
  }
  TILE3(0, KCL(KTILES - 1), 0)  // t = 63
#undef KCL
  asm volatile("s_waitcnt vmcnt(0)" ::: "memory");  // drain before exit

  // --- epilogue: frag j: group g2=j>>2, jj=j&3 -> n = nb + g2*64 + 4c + jj
  const float s = sp[0];
  const float zpf = (float)zpp[0];
  const int m0 = bm * 256 + wr * 128 + (lane >> 4) * 4;
  const int nb4 = bn * 512 + wc * 128 + ((lane & 15) << 2);
  const int4 crA = *(const int4*)(corr + nb4);
  const int4 crB = *(const int4*)(corr + nb4 + 64);
  const float4 swA = *(const float4*)(swp + nb4);
  const float4 swB = *(const float4*)(swp + nb4 + 64);
  const float4 bbA = *(const float4*)(bias + nb4);
  const float4 bbB = *(const float4*)(bias + nb4 + 64);
#pragma unroll
  for (int i = 0; i < 8; ++i) {
#pragma unroll
    for (int q = 0; q < 4; ++q) {
      const int m = m0 + i * 16 + q;
      const float vA0 = s * swA.x * (float)(acc[i][0][q] + crA.x) + bbA.x;
      const float vA1 = s * swA.y * (float)(acc[i][1][q] + crA.y) + bbA.y;
      const float vA2 = s * swA.z * (float)(acc[i][2][q] + crA.z) + bbA.z;
      const float vA3 = s * swA.w * (float)(acc[i][3][q] + crA.w) + bbA.w;
      const float vB0 = s * swB.x * (float)(acc[i][4][q] + crB.x) + bbB.x;
      const float vB1 = s * swB.y * (float)(acc[i][5][q] + crB.y) + bbB.y;
      const float vB2 = s * swB.z * (float)(acc[i][6][q] + crB.z) + bbB.z;
      const float vB3 = s * swB.w * (float)(acc[i][7][q] + crB.w) + bbB.w;
      if (WRITE_Q) {
        const int a0i = (int)fminf(fmaxf(rintf(vA0 / s) + zpf, 0.f), 255.f) - 128;
        const int a1i = (int)fminf(fmaxf(rintf(vA1 / s) + zpf, 0.f), 255.f) - 128;
        const int a2i = (int)fminf(fmaxf(rintf(vA2 / s) + zpf, 0.f), 255.f) - 128;
        const int a3i = (int)fminf(fmaxf(rintf(vA3 / s) + zpf, 0.f), 255.f) - 128;
        const int b0i = (int)fminf(fmaxf(rintf(vB0 / s) + zpf, 0.f), 255.f) - 128;
        const int b1i = (int)fminf(fmaxf(rintf(vB1 / s) + zpf, 0.f), 255.f) - 128;
        const int b2i = (int)fminf(fmaxf(rintf(vB2 / s) + zpf, 0.f), 255.f) - 128;
        const int b3i = (int)fminf(fmaxf(rintf(vB3 / s) + zpf, 0.f), 255.f) - 128;
        const uint32_t pkA = (uint32_t)(a0i & 255) | ((uint32_t)(a1i & 255) << 8) |
                             ((uint32_t)(a2i & 255) << 16) | ((uint32_t)a3i << 24);
        const uint32_t pkB = (uint32_t)(b0i & 255) | ((uint32_t)(b1i & 255) << 8) |
                             ((uint32_t)(b2i & 255) << 16) | ((uint32_t)b3i << 24);
        *(uint32_t*)(outq + (size_t)m * N_DIM + nb4) = pkA;
        *(uint32_t*)(outq + (size_t)m * N_DIM + nb4 + 64) = pkB;
      } else {
        float4 oA, oB;
        oA.x = vA0; oA.y = vA1; oA.z = vA2; oA.w = vA3;
        oB.x = vB0; oB.y = vB1; oB.z = vB2; oB.w = vB3;
        *(float4*)(outf + (size_t)m * N_DIM + nb4) = oA;
        *(float4*)(outf + (size_t)m * N_DIM + nb4 + 64) = oB;
      }
    }
  }
}

// ---------------------------------------------------------------------------
extern "C" void kernel_launch(void* const* d_in, const int* in_sizes, int n_in,
                              void* d_out, int out_size, void* d_ws, size_t ws_size,
                              hipStream_t stream) {
  const float* x = (const float*)d_in[0];
  const int* wq = (const int*)d_in[1];
  const float* bias = (const float*)d_in[2];
  const float* s_in = (const float*)d_in[3];
  const int* zp_in = (const int*)d_in[4];
  const float* s_w = (const float*)d_in[5];
  float* out = (float*)d_out;

  const size_t WP_BYTES = (size_t)N_DIM * K_DIM;  // 16 MB packed int8 W
  const size_t Q_BYTES = (size_t)M_DIM * K_DIM;   // 32 MB int8 activations
  char* ws = (char*)d_ws;
  char* wp = ws;
  char* q1 = ws + WP_BYTES;
  char* q2 = q1 + Q_BYTES;
  int* corr = (int*)(q2 + Q_BYTES);
  const size_t NEEDED = WP_BYTES + 2 * Q_BYTES + (size_t)N_DIM * sizeof(int);
  if (ws_size < NEEDED) return;

  pack_w_kernel<<<N_DIM, 256, 0, stream>>>(wq, wp, corr, zp_in);
  quant_in_kernel<<<(M_DIM * K_DIM / 4) / 256, 256, 0, stream>>>(x, q1, s_in, zp_in);

  dim3 grid((M_DIM / 256) * (N_DIM / 512));  // 256 blocks, 1 per CU
  dim3 blk(512);
  gemm_kernel<1><<<grid, blk, 0, stream>>>(q1, wp, corr, s_w, bias, s_in, zp_in, q2, nullptr);
  gemm_kernel<1><<<grid, blk, 0, stream>>>(q2, wp, corr, s_w, bias, s_in, zp_in, q1, nullptr);
  gemm_kernel<0><<<grid, blk, 0, stream>>>(q1, wp, corr, s_w, bias, s_in, zp_in, nullptr, out);
}

// Round 14
// 440.775 us; speedup vs baseline: 11.6696x; 11.6696x over previous
//
#include <hip/hip_runtime.h>
#include <stdint.h>

#define M_DIM 8192
#define K_DIM 4096
#define N_DIM 4096
#define KTILES (K_DIM / 64)

typedef __attribute__((ext_vector_type(4))) int i32x4;

// ---------------------------------------------------------------------------
// Pack int32-stored int8 weights [N,K] -> true int8 [N,K]; per-row sum folded
// into integer correction corr[n] = (128 - zp) * rowsum[n].
// ---------------------------------------------------------------------------
__global__ void pack_w_kernel(const int* __restrict__ w, char* __restrict__ wp,
                              int* __restrict__ corr, const int* __restrict__ zpp) {
  __shared__ int red[256];
  const int n = blockIdx.x;
  const int t = threadIdx.x;
  const int4* row = (const int4*)(w + (size_t)n * K_DIM);
  int s = 0;
  int words[4];
#pragma unroll
  for (int u = 0; u < 4; ++u) {
    int4 v = row[t * 4 + u];
    s += v.x + v.y + v.z + v.w;
    words[u] = (v.x & 255) | ((v.y & 255) << 8) | ((v.z & 255) << 16) | (v.w << 24);
  }
  ((int4*)(wp + (size_t)n * K_DIM))[t] = make_int4(words[0], words[1], words[2], words[3]);
  red[t] = s;
  __syncthreads();
  for (int off = 128; off > 0; off >>= 1) {
    if (t < off) red[t] += red[t + off];
    __syncthreads();
  }
  if (t == 0) corr[n] = (128 - zpp[0]) * red[0];
}

// ---------------------------------------------------------------------------
// Quantize fp32 input -> int8 (q - 128), 4 elements/thread.
// ---------------------------------------------------------------------------
__global__ void quant_in_kernel(const float* __restrict__ x, char* __restrict__ q,
                                const float* __restrict__ sp, const int* __restrict__ zpp) {
  const int i = blockIdx.x * blockDim.x + threadIdx.x;
  const float s = sp[0];
  const float zp = (float)zpp[0];
  float4 v = ((const float4*)x)[i];
  float t0 = fminf(fmaxf(rintf(v.x / s) + zp, 0.f), 255.f);
  float t1 = fminf(fmaxf(rintf(v.y / s) + zp, 0.f), 255.f);
  float t2 = fminf(fmaxf(rintf(v.z / s) + zp, 0.f), 255.f);
  float t3 = fminf(fmaxf(rintf(v.w / s) + zp, 0.f), 255.f);
  int b0 = (int)t0 - 128, b1 = (int)t1 - 128, b2 = (int)t2 - 128, b3 = (int)t3 - 128;
  ((int*)q)[i] = (b0 & 255) | ((b1 & 255) << 8) | ((b2 & 255) << 16) | (b3 << 24);
}

// ---------------------------------------------------------------------------
// 256x256 i8 GEMM = R3's EXACT schedule (best measured: 135.5us/GEMM,
// MfmaUtil 46%, 0 bank conflicts) + the two proven-orthogonal epilogue
// pieces, unbundled from R11/R12's harmful extras:
//  (a) B content permutation: LDS row (b+16j+r) holds weight row (b+4r+j)
//      (only the staging SOURCE address changes; ds_read pattern and the
//      0-conflict swizzle untouched).
//  (b) Packed full-line epilogue (R9-validated: WRITE_SIZE exactly 32MB):
//      frag j, lane c -> n = base+4c+j consecutive -> one u32 (int8) or
//      one float4 (fp32) store per (i,q).
// NO XCD swizzle (R11: FETCH 98->276MB). NO vmcnt(0)/2-slot (R12: +8us).
// NO sched_barrier pins (R6: null). NO stagger (R8: -30us).
// Geometry: 512 thr = 8 waves (2M x 4N), per-wave 128x64, BK=64 B,
// mfma_i32_16x16x64_i8, 32 MFMA/wave/tile in two 16-clusters (shared b0).
// Registers: acc 128 + ~128 arch = 256/wave -> 2 waves/SIMD (the 512-reg
// pool pins this; R13 proved 8x8 acc spills catastrophically).
// Ring/ledger (R3-proven): 4-slot ring (A16K+B16K)=128KB, prefetch dist 3;
// slots t,t+1 confirmed at tile-t start; vmcnt(4)/tile confirms t+2;
// barrier separates a slot's last reads from its overwrite.
// Swizzle: phys 16B slot = g ^ ((row>>1)&3) on staging source + ds_read.
// ---------------------------------------------------------------------------
#define STAGE16(SRC, DST)                                                     \
  __builtin_amdgcn_global_load_lds(                                           \
      (const __attribute__((address_space(1))) void*)(SRC),                   \
      (__attribute__((address_space(3))) void*)(DST), 16, 0, 0)

#define RD(p) (*(const i32x4*)(p))

#define TILE(SLOT, KSTG, DO_NEXT)                                             \
  {                                                                           \
    const char* bufA_ = &lds[SLOT][0][0];                                     \
    char* nA_ = &lds[((SLOT) + 3) & 3][0][0];                                 \
    char* nB_ = &lds[((SLOT) + 3) & 3][1][0];                                 \
    i32x4 a1_[4];                                                             \
    _Pragma("unroll") for (int i_ = 0; i_ < 4; ++i_)                          \
        a1_[i_] = RD(bufA_ + aoff[4 + i_]);                                   \
    STAGE16(asrc0 + (size_t)(KSTG) * 64, nA_ + o0_);                          \
    STAGE16(asrc1 + (size_t)(KSTG) * 64, nA_ + o1_);                          \
    __builtin_amdgcn_s_setprio(1);                                            \
    _Pragma("unroll") for (int i_ = 0; i_ < 4; ++i_)                          \
        _Pragma("unroll") for (int j_ = 0; j_ < 4; ++j_)                      \
            acc[i_][j_] = __builtin_amdgcn_mfma_i32_16x16x64_i8(              \
                a0[i_], b0[j_], acc[i_][j_], 0, 0, 0);                        \
    __builtin_amdgcn_s_setprio(0);                                            \
    i32x4 ta_[4], tb_[4];                                                     \
    if (DO_NEXT) {                                                            \
      const char* xA_ = &lds[((SLOT) + 1) & 3][0][0];                         \
      const char* xB_ = &lds[((SLOT) + 1) & 3][1][0];                         \
      _Pragma("unroll") for (int i_ = 0; i_ < 4; ++i_)                        \
          ta_[i_] = RD(xA_ + aoff[i_]);                                       \
      _Pragma("unroll") for (int j_ = 0; j_ < 4; ++j_)                        \
          tb_[j_] = RD(xB_ + boff[j_]);                                       \
    }                                                                         \
    STAGE16(bsrc0 + (size_t)(KSTG) * 64, nB_ + o0_);                          \
    STAGE16(bsrc1 + (size_t)(KSTG) * 64, nB_ + o1_);                          \
    __builtin_amdgcn_s_setprio(1);                                            \
    _Pragma("unroll") for (int i_ = 0; i_ < 4; ++i_)                          \
        _Pragma("unroll") for (int j_ = 0; j_ < 4; ++j_)                      \
            acc[4 + i_][j_] = __builtin_amdgcn_mfma_i32_16x16x64_i8(          \
                a1_[i_], b0[j_], acc[4 + i_][j_], 0, 0, 0);                   \
    __builtin_amdgcn_s_setprio(0);                                            \
    asm volatile("s_waitcnt vmcnt(4)" ::: "memory");                          \
    __builtin_amdgcn_s_barrier();                                             \
    if (DO_NEXT) {                                                            \
      _Pragma("unroll") for (int i_ = 0; i_ < 4; ++i_) a0[i_] = ta_[i_];      \
      _Pragma("unroll") for (int j_ = 0; j_ < 4; ++j_) b0[j_] = tb_[j_];      \
    }                                                                         \
  }

template <int WRITE_Q>
__global__ __launch_bounds__(512, 2) void gemm_kernel(
    const char* __restrict__ qa, const char* __restrict__ wb,
    const int* __restrict__ corr, const float* __restrict__ swp,
    const float* __restrict__ bias, const float* __restrict__ sp,
    const int* __restrict__ zpp, char* __restrict__ outq, float* __restrict__ outf) {
  __shared__ __align__(16) char lds[4][2][16384];  // 128 KB: 4-slot ring
  const int tid = threadIdx.x;
  const int lane = tid & 63;
  const int w = tid >> 6;
  const int wr = w >> 2;   // 0..1 (M)
  const int wc = w & 3;    // 0..3 (N)
  const int bid = blockIdx.x;
  const int bm = bid & 31;  // M/256 = 32, fastest: neighbors share B panel
  const int bn = bid >> 5;  // N/256 = 16
  const char* abase = qa + (size_t)bm * 256 * K_DIM;
  const char* bbase = wb + (size_t)bn * 256 * K_DIM;

  // --- per-thread staging constants (inverse-swizzled global sources) ---
  const int o0_ = tid * 16;
  const int o1_ = 8192 + tid * 16;
  const int r0_ = o0_ >> 6, r1_ = o1_ >> 6;
  const int g0_ = ((o0_ >> 4) & 3) ^ ((r0_ >> 1) & 3);
  const int g1_ = ((o1_ >> 4) & 3) ^ ((r1_ >> 1) & 3);
  const char* asrc0 = abase + (size_t)r0_ * K_DIM + g0_ * 16;
  const char* asrc1 = abase + (size_t)r1_ * K_DIM + g1_ * 16;
  // B content permutation: LDS row rho holds weight row (rho&~63)+4*(rho&15)+((rho>>4)&3)
  const int p0_ = (r0_ & ~63) + 4 * (r0_ & 15) + ((r0_ >> 4) & 3);
  const int p1_ = (r1_ & ~63) + 4 * (r1_ & 15) + ((r1_ >> 4) & 3);
  const char* bsrc0 = bbase + (size_t)p0_ * K_DIM + g0_ * 16;
  const char* bsrc1 = bbase + (size_t)p1_ * K_DIM + g1_ * 16;

  // --- per-thread ds_read byte offsets (swizzled) ---
  const int rr = lane & 15;
  const int g = lane >> 4;
  int aoff[8], boff[4];
#pragma unroll
  for (int i = 0; i < 8; ++i) {
    const int row = wr * 128 + i * 16 + rr;
    aoff[i] = (row << 6) + ((g ^ ((row >> 1) & 3)) << 4);
  }
#pragma unroll
  for (int j = 0; j < 4; ++j) {
    const int row = wc * 64 + j * 16 + rr;
    boff[j] = (row << 6) + ((g ^ ((row >> 1) & 3)) << 4);
  }

  i32x4 acc[8][4] = {};

  // --- prologue: stage slots 0,1,2 (tiles 0,1,2); confirm slots 0 AND 1 ---
  STAGE16(asrc0, &lds[0][0][o0_]); STAGE16(asrc1, &lds[0][0][o1_]);
  STAGE16(bsrc0, &lds[0][1][o0_]); STAGE16(bsrc1, &lds[0][1][o1_]);
  STAGE16(asrc0 + 64, &lds[1][0][o0_]); STAGE16(asrc1 + 64, &lds[1][0][o1_]);
  STAGE16(bsrc0 + 64, &lds[1][1][o0_]); STAGE16(bsrc1 + 64, &lds[1][1][o1_]);
  STAGE16(asrc0 + 128, &lds[2][0][o0_]); STAGE16(asrc1 + 128, &lds[2][0][o1_]);
  STAGE16(bsrc0 + 128, &lds[2][1][o0_]); STAGE16(bsrc1 + 128, &lds[2][1][o1_]);
  asm volatile("s_waitcnt vmcnt(4)" ::: "memory");  // slots 0,1 confirmed
  __builtin_amdgcn_s_barrier();

  i32x4 a0[4], b0[4];
#pragma unroll
  for (int i = 0; i < 4; ++i) a0[i] = RD(&lds[0][0][0] + aoff[i]);
#pragma unroll
  for (int j = 0; j < 4; ++j) b0[j] = RD(&lds[0][1][0] + boff[j]);

  // --- main loop: t = 0..59 (slots cycle 0..3) ---
  for (int tb = 0; tb < (KTILES - 4) / 4; ++tb) {
    const int t0 = tb * 4;
#pragma unroll
    for (int u = 0; u < 4; ++u) {
      TILE(u, t0 + u + 3, 1);
    }
  }
  // --- peeled tail: t = 60,61,62,63; stage kt clamps to 63 (re-stage) ---
  TILE(0, KTILES - 1, 1);
  TILE(1, KTILES - 1, 1);
  TILE(2, KTILES - 1, 1);
  TILE(3, KTILES - 1, 0);
  asm volatile("s_waitcnt vmcnt(0)" ::: "memory");  // drain before exit

  // --- epilogue (R9-validated): frag j, lane c -> n = nb4 + j ---
  const float s = sp[0];
  const float zpf = (float)zpp[0];
  const int m0 = bm * 256 + wr * 128 + (lane >> 4) * 4;
  const int nb4 = bn * 256 + wc * 64 + ((lane & 15) << 2);
  const int4 cr4 = *(const int4*)(corr + nb4);
  const float4 sw4 = *(const float4*)(swp + nb4);
  const float4 bb4 = *(const float4*)(bias + nb4);
  const float fs0 = s * sw4.x, fs1 = s * sw4.y, fs2 = s * sw4.z, fs3 = s * sw4.w;
#pragma unroll
  for (int i = 0; i < 8; ++i) {
#pragma unroll
    for (int q = 0; q < 4; ++q) {
      const int m = m0 + i * 16 + q;
      const float v0 = fs0 * (float)(acc[i][0][q] + cr4.x) + bb4.x;
      const float v1 = fs1 * (float)(acc[i][1][q] + cr4.y) + bb4.y;
      const float v2 = fs2 * (float)(acc[i][2][q] + cr4.z) + bb4.z;
      const float v3 = fs3 * (float)(acc[i][3][q] + cr4.w) + bb4.w;
      if (WRITE_Q) {
        const int b0i = (int)fminf(fmaxf(rintf(v0 / s) + zpf, 0.f), 255.f) - 128;
        const int b1i = (int)fminf(fmaxf(rintf(v1 / s) + zpf, 0.f), 255.f) - 128;
        const int b2i = (int)fminf(fmaxf(rintf(v2 / s) + zpf, 0.f), 255.f) - 128;
        const int b3i = (int)fminf(fmaxf(rintf(v3 / s) + zpf, 0.f), 255.f) - 128;
        const uint32_t pk = (uint32_t)(b0i & 255) | ((uint32_t)(b1i & 255) << 8) |
                            ((uint32_t)(b2i & 255) << 16) | ((uint32_t)b3i << 24);
        *(uint32_t*)(outq + (size_t)m * N_DIM + nb4) = pk;
      } else {
        float4 o4;
        o4.x = v0; o4.y = v1; o4.z = v2; o4.w = v3;
        *(float4*)(outf + (size_t)m * N_DIM + nb4) = o4;
      }
    }
  }
}

// ---------------------------------------------------------------------------
extern "C" void kernel_launch(void* const* d_in, const int* in_sizes, int n_in,
                              void* d_out, int out_size, void* d_ws, size_t ws_size,
                              hipStream_t stream) {
  const float* x = (const float*)d_in[0];
  const int* wq = (const int*)d_in[1];
  const float* bias = (const float*)d_in[2];
  const float* s_in = (const float*)d_in[3];
  const int* zp_in = (const int*)d_in[4];
  const float* s_w = (const float*)d_in[5];
  float* out = (float*)d_out;

  const size_t WP_BYTES = (size_t)N_DIM * K_DIM;  // 16 MB packed int8 W
  const size_t Q_BYTES = (size_t)M_DIM * K_DIM;   // 32 MB int8 activations
  char* ws = (char*)d_ws;
  char* wp = ws;
  char* q1 = ws + WP_BYTES;
  char* q2 = q1 + Q_BYTES;
  int* corr = (int*)(q2 + Q_BYTES);
  const size_t NEEDED = WP_BYTES + 2 * Q_BYTES + (size_t)N_DIM * sizeof(int);
  if (ws_size < NEEDED) return;

  pack_w_kernel<<<N_DIM, 256, 0, stream>>>(wq, wp, corr, zp_in);
  quant_in_kernel<<<(M_DIM * K_DIM / 4) / 256, 256, 0, stream>>>(x, q1, s_in, zp_in);

  dim3 grid((M_DIM / 256) * (N_DIM / 256));  // 512 blocks
  dim3 blk(512);
  gemm_kernel<1><<<grid, blk, 0, stream>>>(q1, wp, corr, s_w, bias, s_in, zp_in, q2, nullptr);
  gemm_kernel<1><<<grid, blk, 0, stream>>>(q2, wp, corr, s_w, bias, s_in, zp_in, q1, nullptr);
  gemm_kernel<0><<<grid, blk, 0, stream>>>(q1, wp, corr, s_w, bias, s_in, zp_in, nullptr, out);
}

// Round 15
// 438.801 us; speedup vs baseline: 11.7220x; 1.0045x over previous
//
#include <hip/hip_runtime.h>
#include <stdint.h>

#define M_DIM 8192
#define K_DIM 4096
#define N_DIM 4096
#define KTILES (K_DIM / 64)

typedef __attribute__((ext_vector_type(4))) int i32x4;

// ---------------------------------------------------------------------------
// Pack int32-stored int8 weights [N,K] -> true int8 [N,K]; per-row sum folded
// into integer correction corr[n] = (128 - zp) * rowsum[n].
// ---------------------------------------------------------------------------
__global__ void pack_w_kernel(const int* __restrict__ w, char* __restrict__ wp,
                              int* __restrict__ corr, const int* __restrict__ zpp) {
  __shared__ int red[256];
  const int n = blockIdx.x;
  const int t = threadIdx.x;
  const int4* row = (const int4*)(w + (size_t)n * K_DIM);
  int s = 0;
  int words[4];
#pragma unroll
  for (int u = 0; u < 4; ++u) {
    int4 v = row[t * 4 + u];
    s += v.x + v.y + v.z + v.w;
    words[u] = (v.x & 255) | ((v.y & 255) << 8) | ((v.z & 255) << 16) | (v.w << 24);
  }
  ((int4*)(wp + (size_t)n * K_DIM))[t] = make_int4(words[0], words[1], words[2], words[3]);
  red[t] = s;
  __syncthreads();
  for (int off = 128; off > 0; off >>= 1) {
    if (t < off) red[t] += red[t + off];
    __syncthreads();
  }
  if (t == 0) corr[n] = (128 - zpp[0]) * red[0];
}

// ---------------------------------------------------------------------------
// Quantize fp32 input -> int8 (q - 128), 4 elements/thread.
// ---------------------------------------------------------------------------
__global__ void quant_in_kernel(const float* __restrict__ x, char* __restrict__ q,
                                const float* __restrict__ sp, const int* __restrict__ zpp) {
  const int i = blockIdx.x * blockDim.x + threadIdx.x;
  const float s = sp[0];
  const float zp = (float)zpp[0];
  float4 v = ((const float4*)x)[i];
  float t0 = fminf(fmaxf(rintf(v.x / s) + zp, 0.f), 255.f);
  float t1 = fminf(fmaxf(rintf(v.y / s) + zp, 0.f), 255.f);
  float t2 = fminf(fmaxf(rintf(v.z / s) + zp, 0.f), 255.f);
  float t3 = fminf(fmaxf(rintf(v.w / s) + zp, 0.f), 255.f);
  int b0 = (int)t0 - 128, b1 = (int)t1 - 128, b2 = (int)t2 - 128, b3 = (int)t3 - 128;
  ((int*)q)[i] = (b0 & 255) | ((b1 & 255) << 8) | ((b2 & 255) << 16) | (b3 << 24);
}

// ---------------------------------------------------------------------------
// 256x256 i8 GEMM, 1024 threads = 16 waves (4M x 4N), 64x64 out per wave,
// FOUR waves per SIMD. Rationale: R3-R14's 8-wave config sits at the exact
// 256-reg/wave cap -> 2 waves/SIMD -> no TLP to overlap LDS reads with MFMA
// (floor 134us, MfmaUtil 46%). Thin waves: acc 4x4 frags = 64 AGPR, arch
// budget 64 VGPR (live set ~52: 32 frag + addrs). No register pipelining --
// per tile {8 ds_reads -> 2 stages -> 16 MFMA -> vmcnt(2) -> barrier};
// latency hiding via 4-way wave TLP per SIMD (m114 mechanism).
// LDS: 4-slot ring (A16K+B16K) = 128 KB, 1 block/CU. Staging: 1024 thr x
// 16B = whole 16KB tile in ONE gload_lds per matrix.
// Ledger (2 stages/tile, dist 3): stage during t targets slot (t+3)&3 =
// slot (t-1)&3 whose reads finished before t-1's end barrier. vmcnt(2) at
// tile-t end retires stages <= t-1 -> slot t+2 confirmed; reads at start of
// tile t use slot t (confirmed at end of t-2). Prologue stages slots 0,1,2,
// vmcnt(2) confirms 0,1. Tail: t=60 stages k=63 into slot 3 (read by t=63);
// t=61..63 dead re-stages of k=63 into slots 0,1,2 (never read again).
// Swizzle (0-conflict R1-R14): phys 16B slot = g ^ ((row>>1)&3) on staging
// source and ds_read addr. B content permutation (R8/R9-validated): LDS row
// rho holds weight row (rho&~63)+4*(rho&15)+((rho>>4)&3) -> epilogue n =
// base+4c+j consecutive -> packed full-line stores.
// ---------------------------------------------------------------------------
#define STAGE16(SRC, DST)                                                     \
  __builtin_amdgcn_global_load_lds(                                           \
      (const __attribute__((address_space(1))) void*)(SRC),                   \
      (__attribute__((address_space(3))) void*)(DST), 16, 0, 0)

#define RD(p) (*(const i32x4*)(p))

#define TILE4(SLOT, KS)                                                       \
  {                                                                           \
    const char* cA_ = &lds[SLOT][0][0];                                       \
    const char* cB_ = &lds[SLOT][1][0];                                       \
    char* nA_ = &lds[((SLOT) + 3) & 3][0][0];                                 \
    char* nB_ = &lds[((SLOT) + 3) & 3][1][0];                                 \
    i32x4 a_[4], b_[4];                                                       \
    _Pragma("unroll") for (int i_ = 0; i_ < 4; ++i_)                          \
        a_[i_] = RD(cA_ + aoff[i_]);                                          \
    _Pragma("unroll") for (int j_ = 0; j_ < 4; ++j_)                          \
        b_[j_] = RD(cB_ + boff[j_]);                                          \
    STAGE16(asrc0 + (size_t)(KS), nA_ + o0_);                                 \
    STAGE16(bsrc0 + (size_t)(KS), nB_ + o0_);                                 \
    __builtin_amdgcn_s_setprio(1);                                            \
    _Pragma("unroll") for (int i_ = 0; i_ < 4; ++i_)                          \
        _Pragma("unroll") for (int j_ = 0; j_ < 4; ++j_)                      \
            acc[i_][j_] = __builtin_amdgcn_mfma_i32_16x16x64_i8(              \
                a_[i_], b_[j_], acc[i_][j_], 0, 0, 0);                        \
    __builtin_amdgcn_s_setprio(0);                                            \
    asm volatile("s_waitcnt vmcnt(2)" ::: "memory");                          \
    __builtin_amdgcn_s_barrier();                                             \
  }

template <int WRITE_Q>
__global__ __launch_bounds__(1024, 4) void gemm_kernel(
    const char* __restrict__ qa, const char* __restrict__ wb,
    const int* __restrict__ corr, const float* __restrict__ swp,
    const float* __restrict__ bias, const float* __restrict__ sp,
    const int* __restrict__ zpp, char* __restrict__ outq, float* __restrict__ outf) {
  __shared__ __align__(16) char lds[4][2][16384];  // 128 KB: 4-slot ring
  const int tid = threadIdx.x;
  const int lane = tid & 63;
  const int w = tid >> 6;   // 16 waves
  const int wr = w >> 2;    // 0..3 (M, 64 each)
  const int wc = w & 3;     // 0..3 (N, 64 each)
  const int bid = blockIdx.x;
  const int bm = bid & 31;  // M/256 = 32, fastest: neighbors share B panel
  const int bn = bid >> 5;  // N/256 = 16
  const char* abase = qa + (size_t)bm * 256 * K_DIM;
  const char* bbase = wb + (size_t)bn * 256 * K_DIM;

  // --- staging constants: 1024 thr x 16B = 16 KB (whole matrix tile) ---
  const int o0_ = tid * 16;
  const int r0_ = tid >> 2;            // tile row 0..255
  const int sl_ = tid & 3;             // 16B slot within row
  const int g0_ = sl_ ^ ((r0_ >> 1) & 3);
  const char* asrc0 = abase + (size_t)r0_ * K_DIM + g0_ * 16;
  // B content permutation: LDS row rho holds weight row (rho&~63)+4*(rho&15)+((rho>>4)&3)
  const int p0_ = (r0_ & ~63) + 4 * (r0_ & 15) + ((r0_ >> 4) & 3);
  const char* bsrc0 = bbase + (size_t)p0_ * K_DIM + g0_ * 16;

  // --- per-lane ds_read byte offsets (swizzled) ---
  const int rr = lane & 15;
  const int g = lane >> 4;
  int aoff[4], boff[4];
#pragma unroll
  for (int i = 0; i < 4; ++i) {
    const int rowA = wr * 64 + i * 16 + rr;
    aoff[i] = (rowA << 6) + ((g ^ ((rowA >> 1) & 3)) << 4);
    const int rowB = wc * 64 + i * 16 + rr;
    boff[i] = (rowB << 6) + ((g ^ ((rowB >> 1) & 3)) << 4);
  }

  i32x4 acc[4][4] = {};

  // --- prologue: stage slots 0,1,2 (6 ops); vmcnt(2) confirms slots 0,1 ---
  STAGE16(asrc0, &lds[0][0][o0_]);       STAGE16(bsrc0, &lds[0][1][o0_]);
  STAGE16(asrc0 + 64, &lds[1][0][o0_]);  STAGE16(bsrc0 + 64, &lds[1][1][o0_]);
  STAGE16(asrc0 + 128, &lds[2][0][o0_]); STAGE16(bsrc0 + 128, &lds[2][1][o0_]);
  asm volatile("s_waitcnt vmcnt(2)" ::: "memory");
  __builtin_amdgcn_s_barrier();

  // --- main loop: 64 uniform tiles (4-unrolled; clamped tail re-stages) ---
#define KCL(x) ((size_t)((x) < KTILES ? (x) : KTILES - 1) * 64)
  for (int tb = 0; tb < KTILES / 4; ++tb) {
    const int t0 = tb * 4;
    TILE4(0, KCL(t0 + 3))
    TILE4(1, KCL(t0 + 4))
    TILE4(2, KCL(t0 + 5))
    TILE4(3, KCL(t0 + 6))
  }
#undef KCL
  asm volatile("s_waitcnt vmcnt(0)" ::: "memory");  // drain before exit

  // --- epilogue (R9-validated): frag j, lane c -> n = nb4 + j ---
  const float s = sp[0];
  const float zpf = (float)zpp[0];
  const int m0 = bm * 256 + wr * 64 + (lane >> 4) * 4;
  const int nb4 = bn * 256 + wc * 64 + ((lane & 15) << 2);
  const int4 cr4 = *(const int4*)(corr + nb4);
  const float4 sw4 = *(const float4*)(swp + nb4);
  const float4 bb4 = *(const float4*)(bias + nb4);
  const float fs0 = s * sw4.x, fs1 = s * sw4.y, fs2 = s * sw4.z, fs3 = s * sw4.w;
#pragma unroll
  for (int i = 0; i < 4; ++i) {
#pragma unroll
    for (int q = 0; q < 4; ++q) {
      const int m = m0 + i * 16 + q;
      const float v0 = fs0 * (float)(acc[i][0][q] + cr4.x) + bb4.x;
      const float v1 = fs1 * (float)(acc[i][1][q] + cr4.y) + bb4.y;
      const float v2 = fs2 * (float)(acc[i][2][q] + cr4.z) + bb4.z;
      const float v3 = fs3 * (float)(acc[i][3][q] + cr4.w) + bb4.w;
      if (WRITE_Q) {
        const int b0i = (int)fminf(fmaxf(rintf(v0 / s) + zpf, 0.f), 255.f) - 128;
        const int b1i = (int)fminf(fmaxf(rintf(v1 / s) + zpf, 0.f), 255.f) - 128;
        const int b2i = (int)fminf(fmaxf(rintf(v2 / s) + zpf, 0.f), 255.f) - 128;
        const int b3i = (int)fminf(fmaxf(rintf(v3 / s) + zpf, 0.f), 255.f) - 128;
        const uint32_t pk = (uint32_t)(b0i & 255) | ((uint32_t)(b1i & 255) << 8) |
                            ((uint32_t)(b2i & 255) << 16) | ((uint32_t)b3i << 24);
        *(uint32_t*)(outq + (size_t)m * N_DIM + nb4) = pk;
      } else {
        float4 o4;
        o4.x = v0; o4.y = v1; o4.z = v2; o4.w = v3;
        *(float4*)(outf + (size_t)m * N_DIM + nb4) = o4;
      }
    }
  }
}

// ---------------------------------------------------------------------------
extern "C" void kernel_launch(void* const* d_in, const int* in_sizes, int n_in,
                              void* d_out, int out_size, void* d_ws, size_t ws_size,
                              hipStream_t stream) {
  const float* x = (const float*)d_in[0];
  const int* wq = (const int*)d_in[1];
  const float* bias = (const float*)d_in[2];
  const float* s_in = (const float*)d_in[3];
  const int* zp_in = (const int*)d_in[4];
  const float* s_w = (const float*)d_in[5];
  float* out = (float*)d_out;

  const size_t WP_BYTES = (size_t)N_DIM * K_DIM;  // 16 MB packed int8 W
  const size_t Q_BYTES = (size_t)M_DIM * K_DIM;   // 32 MB int8 activations
  char* ws = (char*)d_ws;
  char* wp = ws;
  char* q1 = ws + WP_BYTES;
  char* q2 = q1 + Q_BYTES;
  int* corr = (int*)(q2 + Q_BYTES);
  const size_t NEEDED = WP_BYTES + 2 * Q_BYTES + (size_t)N_DIM * sizeof(int);
  if (ws_size < NEEDED) return;

  pack_w_kernel<<<N_DIM, 256, 0, stream>>>(wq, wp, corr, zp_in);
  quant_in_kernel<<<(M_DIM * K_DIM / 4) / 256, 256, 0, stream>>>(x, q1, s_in, zp_in);

  dim3 grid((M_DIM / 256) * (N_DIM / 256));  // 512 blocks
  dim3 blk(1024);
  gemm_kernel<1><<<grid, blk, 0, stream>>>(q1, wp, corr, s_w, bias, s_in, zp_in, q2, nullptr);
  gemm_kernel<1><<<grid, blk, 0, stream>>>(q2, wp, corr, s_w, bias, s_in, zp_in, q1, nullptr);
  gemm_kernel<0><<<grid, blk, 0, stream>>>(q1, wp, corr, s_w, bias, s_in, zp_in, nullptr, out);
}